// Round 18
// baseline (176.163 us; speedup 1.0000x reference)
//
#include <hip/hip_runtime.h>

typedef __bf16 bf16;
typedef __bf16 bf16x8 __attribute__((ext_vector_type(8)));
typedef __bf16 bf16x4 __attribute__((ext_vector_type(4)));
typedef float f32x4 __attribute__((ext_vector_type(4)));

#if __has_builtin(__builtin_amdgcn_exp2f)
#define EXP2(x) __builtin_amdgcn_exp2f(x)
#else
#define EXP2(x) exp2f(x)
#endif

__device__ __forceinline__ void gload_lds16(const void* g, void* l) {
  __builtin_amdgcn_global_load_lds(
      (const __attribute__((address_space(1))) void*)g,
      (__attribute__((address_space(3))) void*)l, 16, 0, 0);
}

// One kernel casts all three inputs (HBM-BW-bound: 120MB ~ 19us).
__global__ __launch_bounds__(256) void cast_all(const float* __restrict__ x,
                                                const float* __restrict__ wqkv,
                                                const float* __restrict__ wout,
                                                bf16* __restrict__ x_bf,
                                                bf16* __restrict__ wqkv_bf,
                                                bf16* __restrict__ wout_bf) {
  const int b = blockIdx.x;
  const float* src;
  bf16* dst;
  int i;
  if (b < 4096) {
    src = x; dst = x_bf; i = b * 1024 + threadIdx.x * 4;
  } else if (b < 16384) {
    src = wqkv; dst = wqkv_bf; i = (b - 4096) * 1024 + threadIdx.x * 4;
  } else {
    src = wout; dst = wout_bf; i = (b - 16384) * 1024 + threadIdx.x * 4;
  }
  float4 v = *(const float4*)(src + i);
  bf16x4 o = {(bf16)v.x, (bf16)v.y, (bf16)v.z, (bf16)v.w};
  *(bf16x4*)(dst + i) = o;
}

// ---------------------------------------------------------------------------
// GEMM1 (known-good, 69.4us): qkv = x @ w_qkv^T.  m97 128^2, BK=32, constexpr
// dims.  FROZEN: r4/r7/r8/r11/r15/r16 restructures all regressed.
// ---------------------------------------------------------------------------
__global__ __launch_bounds__(256) void gemm1_qkv(const bf16* __restrict__ A,
                                                 const bf16* __restrict__ B,
                                                 bf16* __restrict__ qb,
                                                 bf16* __restrict__ kb,
                                                 bf16* __restrict__ vt) {
  constexpr int K = 2048;
  __shared__ bf16 As[128 * 32];
  __shared__ bf16 Bs[128 * 32];
  const int t = threadIdx.x;
  const int w = t >> 6, l = t & 63;
  const int lr = l & 15, lg = l >> 4;
  const int nwg = 768;
  int lin = blockIdx.y * 48 + blockIdx.x;
  lin = (lin & 7) * (nwg >> 3) + (lin >> 3);  // XCD-bijective
  const int bn = lin % 48;
  const int bm = lin / 48;
  const int wr = w >> 1, wc = w & 1;

  f32x4 acc[4][4] = {};
  const int row0 = t >> 2;
  const int cc0 = (t & 3) * 8;

  for (int k0 = 0; k0 < K; k0 += 32) {
#pragma unroll
    for (int r = 0; r < 2; ++r) {
      const int row = r * 64 + row0;
      gload_lds16(A + (size_t)(bm * 128 + row) * K + k0 + cc0,
                  (char*)As + (r * 256 + w * 64) * 16);
      gload_lds16(B + (size_t)(bn * 128 + row) * K + k0 + cc0,
                  (char*)Bs + (r * 256 + w * 64) * 16);
    }
    __syncthreads();
    bf16x8 af[4], bfr[4];
#pragma unroll
    for (int i = 0; i < 4; ++i) {
      af[i] = *(const bf16x8*)((const char*)As + (wr * 64 + i * 16 + lr) * 64 + lg * 16);
      bfr[i] = *(const bf16x8*)((const char*)Bs + (wc * 64 + i * 16 + lr) * 64 + lg * 16);
    }
#pragma unroll
    for (int mi = 0; mi < 4; ++mi)
#pragma unroll
      for (int ni = 0; ni < 4; ++ni)
        acc[mi][ni] = __builtin_amdgcn_mfma_f32_16x16x32_bf16(af[mi], bfr[ni],
                                                              acc[mi][ni], 0, 0, 0);
    __syncthreads();
  }

  const int mb = bm * 128 + wr * 64 + lg * 4;
  const int nb = bn * 128 + wc * 64 + lr;
  if (bn * 128 < 4096) {
    bf16* dst = (bn * 128 < 2048) ? qb : kb;
#pragma unroll
    for (int mi = 0; mi < 4; ++mi) {
      const int mg = mb + mi * 16;
#pragma unroll
      for (int ni = 0; ni < 4; ++ni) {
        const int ng = (nb + ni * 16) & 2047;
#pragma unroll
        for (int rr = 0; rr < 4; ++rr)
          dst[(size_t)(mg + rr) * 2048 + ng] = (bf16)acc[mi][ni][rr];
      }
    }
  } else {
#pragma unroll
    for (int mi = 0; mi < 4; ++mi) {
      const int mg = mb + mi * 16;
#pragma unroll
      for (int ni = 0; ni < 4; ++ni) {
        const int dc = nb + ni * 16 - 4096;
        bf16x4 pk = {(bf16)acc[mi][ni][0], (bf16)acc[mi][ni][1],
                     (bf16)acc[mi][ni][2], (bf16)acc[mi][ni][3]};
        *(bf16x4*)(vt + (size_t)dc * 2048 + mg) = pk;
      }
    }
  }
}

// ---------------------------------------------------------------------------
// GEMM2 (known-good): out = attn @ w_out^T, f32.  64x128 tile, 512 blocks.
// ---------------------------------------------------------------------------
__global__ __launch_bounds__(256) void gemm2_64x128(const bf16* __restrict__ A,
                                                    const bf16* __restrict__ B,
                                                    float* __restrict__ Cf) {
  constexpr int K = 2048, N = 2048;
  __shared__ bf16 As[64 * 32];
  __shared__ bf16 Bs[128 * 32];
  const int t = threadIdx.x;
  const int w = t >> 6, l = t & 63;
  const int lr = l & 15, lg = l >> 4;
  int lin = blockIdx.y * 16 + blockIdx.x;
  lin = (lin & 7) * 64 + (lin >> 3);  // XCD-bijective
  const int bn = lin % 16;
  const int bm = lin / 16;

  f32x4 acc[4][2] = {};

  for (int k0 = 0; k0 < K; k0 += 32) {
    {
      const int row = t >> 2;
      gload_lds16(A + (size_t)(bm * 64 + row) * K + k0 + (t & 3) * 8,
                  (char*)As + (w * 64) * 16);
    }
#pragma unroll
    for (int r = 0; r < 2; ++r) {
      const int c = r * 256 + t;
      const int row = c >> 2;
      gload_lds16(B + (size_t)(bn * 128 + row) * K + k0 + (c & 3) * 8,
                  (char*)Bs + (r * 256 + w * 64) * 16);
    }
    __syncthreads();
    bf16x8 af[4], bfr[2];
#pragma unroll
    for (int i = 0; i < 4; ++i)
      af[i] = *(const bf16x8*)((const char*)As + (i * 16 + lr) * 64 + lg * 16);
#pragma unroll
    for (int i = 0; i < 2; ++i)
      bfr[i] = *(const bf16x8*)((const char*)Bs + (w * 32 + i * 16 + lr) * 64 + lg * 16);
#pragma unroll
    for (int mi = 0; mi < 4; ++mi)
#pragma unroll
      for (int ni = 0; ni < 2; ++ni)
        acc[mi][ni] = __builtin_amdgcn_mfma_f32_16x16x32_bf16(af[mi], bfr[ni],
                                                              acc[mi][ni], 0, 0, 0);
    __syncthreads();
  }

  const int mb = bm * 64 + lg * 4;
  const int nb = bn * 128 + w * 32 + lr;
#pragma unroll
  for (int mi = 0; mi < 4; ++mi) {
    const int mg = mb + mi * 16;
#pragma unroll
    for (int ni = 0; ni < 2; ++ni) {
      const int ng = nb + ni * 16;
#pragma unroll
      for (int rr = 0; rr < 4; ++rr)
        Cf[(size_t)(mg + rr) * N + ng] = acc[mi][ni][rr];
    }
  }
}

// ---------------------------------------------------------------------------
// Flash attention, QBLK=128 (8 waves / 512 thr), causal + ALiBi + window W=24,
// tiered KV split; single-buffered LDS staging (48KB).  Per 64-col KV tile the
// staged 24KB now feeds 2x the compute (vs QBLK=64) and stage issue width is
// 2x -> stage fraction ~halves; pieces 1408 -> 736.
// Grid 736:
//   b in [0,512):   4-way piece b&3 of job j=b>>2   (h=j&15, qt2=8+(j>>4))
//   b in [512,704): 2-way piece of job j=(b-512)>>1 (h=j&15, qt2=2+(j>>4))
//   b in [704,736): single i=b-704                  (h=i&15, qt2=i>>4 < 2)
// Split pieces: bf16 partials (128x128) + f32 m/l; merge combines exactly.
// Mask is unconditional (two tiles/job straddle the diagonal).  Fully-masked
// pieces yield m=-1e30 -> merge weight 0 (safe).
// ---------------------------------------------------------------------------
__global__ __launch_bounds__(512) void attn_kernel(const bf16* __restrict__ qb,
                                                   const bf16* __restrict__ kb,
                                                   const bf16* __restrict__ vt,
                                                   bf16* __restrict__ out,
                                                   bf16* __restrict__ pA,
                                                   bf16* __restrict__ pB,
                                                   float* __restrict__ ml) {
  constexpr int S = 2048, D = 2048;
  __shared__ bf16 Ks[64 * 128];
  __shared__ bf16 Vs[128 * 64];
  __shared__ bf16 Ps[8][16 * 64];
  const int t = threadIdx.x;
  const int w = t >> 6, l = t & 63;
  const int lr = l & 15, lg = l >> 4;
  const int b = blockIdx.x;

  int h, qt2, piece, ns;
  if (b < 512) {
    const int j = b >> 2;
    h = j & 15; qt2 = 8 + (j >> 4); piece = b & 3; ns = 4;
  } else if (b < 704) {
    const int u = b - 512;
    const int j = u >> 1;
    h = j & 15; qt2 = 2 + (j >> 4); piece = u & 1; ns = 2;
  } else {
    const int i = b - 704;
    h = i & 15; qt2 = i >> 4; piece = 0; ns = 1;
  }
  const bool split = (ns > 1);
  const int q0 = qt2 * 128;
  const float slope2 = exp2f(-0.5f * (float)(h + 1)) * 1.4426950408889634f;
  const float scale2 = 0.08838834764831845f * 1.4426950408889634f;
  const int W = (int)(24.0f / slope2);
  const int s0 = (q0 > W) ? ((q0 - W) >> 6) : 0;
  const int endt = 2 * qt2 + 2;
  const int len = endt - s0;
  const int start = s0 + (len * piece) / ns;
  const int pend = s0 + (len * (piece + 1)) / ns;

  bf16x8 qf[4];
  {
    const bf16* qrow = qb + (size_t)(q0 + w * 16 + lr) * D + h * 128 + lg * 8;
#pragma unroll
    for (int kk = 0; kk < 4; ++kk) qf[kk] = *(const bf16x8*)(qrow + kk * 32);
  }

  f32x4 ob[8] = {};
  float mrow[4] = {-1e30f, -1e30f, -1e30f, -1e30f};
  float lrow[4] = {0.f, 0.f, 0.f, 0.f};

  auto stage = [&](int kv0) {
#pragma unroll
    for (int r = 0; r < 2; ++r) {  // K [64 rows][16 chunks]: 1024 chunks
      const int c = r * 512 + t;
      const int krow = c >> 4;
      const int kcc = c & 15;
      gload_lds16(kb + (size_t)(kv0 + krow) * D + h * 128 + ((kcc ^ (krow & 7)) * 8),
                  (char*)Ks + (r * 512 + w * 64) * 16);
    }
#pragma unroll
    for (int r = 0; r < 2; ++r) {  // V [128 rows][8 chunks]: 1024 chunks
      const int c = r * 512 + t;
      const int vrow = c >> 3;
      const int vcc = c & 7;
      gload_lds16(vt + (size_t)(h * 128 + vrow) * S + kv0 + ((vcc ^ (vrow & 7)) * 8),
                  (char*)Vs + (r * 512 + w * 64) * 16);
    }
  };

  for (int tile = start; tile < pend; ++tile) {
    const int kv0 = tile << 6;
    stage(kv0);
    __syncthreads();

    f32x4 sc[4] = {};
    __builtin_amdgcn_s_setprio(1);
#pragma unroll
    for (int jb = 0; jb < 4; ++jb) {
      const int row = jb * 16 + lr;
#pragma unroll
      for (int kk = 0; kk < 4; ++kk) {
        const int byte = row * 256 + ((kk * 64 + lg * 16) ^ ((row & 7) << 4));
        bf16x8 kf = *(const bf16x8*)((const char*)Ks + byte);
        sc[jb] = __builtin_amdgcn_mfma_f32_16x16x32_bf16(qf[kk], kf, sc[jb], 0, 0, 0);
      }
    }
    __builtin_amdgcn_s_setprio(0);

    float bias[4];
#pragma unroll
    for (int jb = 0; jb < 4; ++jb)
      bias[jb] = slope2 * (float)(kv0 + jb * 16 + lr - (S - 1));
    float xv[4][4], m2r[4];
#pragma unroll
    for (int rr = 0; rr < 4; ++rr) {
      const int i = q0 + w * 16 + lg * 4 + rr;
#pragma unroll
      for (int jb = 0; jb < 4; ++jb) {
        float v = fmaf(sc[jb][rr], scale2, bias[jb]);
        if (kv0 + jb * 16 + lr > i) v = -1e30f;  // unconditional causal mask
        xv[rr][jb] = v;
      }
      float m2 = fmaxf(fmaxf(xv[rr][0], xv[rr][1]), fmaxf(xv[rr][2], xv[rr][3]));
      m2 = fmaxf(m2, __shfl_xor(m2, 1));
      m2 = fmaxf(m2, __shfl_xor(m2, 2));
      m2 = fmaxf(m2, __shfl_xor(m2, 4));
      m2 = fmaxf(m2, __shfl_xor(m2, 8));
      m2r[rr] = m2;
    }
    float need = fmaxf(fmaxf(m2r[0] - mrow[0], m2r[1] - mrow[1]),
                       fmaxf(m2r[2] - mrow[2], m2r[3] - mrow[3]));
    if (!__all(need <= 8.0f)) {
#pragma unroll
      for (int rr = 0; rr < 4; ++rr) {
        const float mnew = fmaxf(mrow[rr], m2r[rr]);
        const float cf = EXP2(mrow[rr] - mnew);
        lrow[rr] *= cf;
        mrow[rr] = mnew;
#pragma unroll
        for (int db = 0; db < 8; ++db) ob[db][rr] *= cf;
      }
    }
    char* pbase = (char*)Ps[w];
#pragma unroll
    for (int rr = 0; rr < 4; ++rr) {
      const int prow = lg * 4 + rr;
      const int sw = (prow & 7) << 4;
      float ps = 0.f;
#pragma unroll
      for (int jb = 0; jb < 4; ++jb) {
        const float p = EXP2(xv[rr][jb] - mrow[rr]);
        *(bf16*)(pbase + ((prow * 128 + jb * 32 + lr * 2) ^ sw)) = (bf16)p;
        ps += p;
      }
      lrow[rr] += ps;
    }

    bf16x8 pf[2];
#pragma unroll
    for (int s = 0; s < 2; ++s)
      pf[s] = *(const bf16x8*)(pbase + ((lr * 128 + s * 64 + lg * 16) ^ ((lr & 7) << 4)));
    __builtin_amdgcn_s_setprio(1);
#pragma unroll
    for (int db = 0; db < 8; ++db) {
      const int vrow = db * 16 + lr;
#pragma unroll
      for (int s = 0; s < 2; ++s) {
        const int byte = vrow * 128 + ((s * 64 + lg * 16) ^ ((vrow & 7) << 4));
        bf16x8 vf = *(const bf16x8*)((const char*)Vs + byte);
        ob[db] = __builtin_amdgcn_mfma_f32_16x16x32_bf16(pf[s], vf, ob[db], 0, 0, 0);
      }
    }
    __builtin_amdgcn_s_setprio(0);
    __syncthreads();
  }

  if (!split) {
#pragma unroll
    for (int rr = 0; rr < 4; ++rr) {
      float ls = lrow[rr];
      ls += __shfl_xor(ls, 1);
      ls += __shfl_xor(ls, 2);
      ls += __shfl_xor(ls, 4);
      ls += __shfl_xor(ls, 8);
      const float inv = 1.0f / ls;
      const int mg = q0 + w * 16 + lg * 4 + rr;
#pragma unroll
      for (int db = 0; db < 8; ++db)
        out[(size_t)mg * D + h * 128 + db * 16 + lr] = (bf16)(ob[db][rr] * inv);
    }
  } else {
    bf16* po = (b < 512) ? pA + (size_t)b * 16384 : pB + (size_t)(b - 512) * 16384;
#pragma unroll
    for (int rr = 0; rr < 4; ++rr) {
      float ls = lrow[rr];
      ls += __shfl_xor(ls, 1);
      ls += __shfl_xor(ls, 2);
      ls += __shfl_xor(ls, 4);
      ls += __shfl_xor(ls, 8);
      const int row = w * 16 + lg * 4 + rr;  // 0..127
#pragma unroll
      for (int db = 0; db < 8; ++db)
        po[row * 128 + db * 16 + lr] = (bf16)ob[db][rr];
      if (lr == 0) {
        ml[b * 256 + row] = mrow[rr];
        ml[b * 256 + 128 + row] = ls;
      }
    }
  }
}

// Merge ns KV pieces of a split job (exact log-sum-exp combine), 128 rows/job.
__global__ __launch_bounds__(256) void attn_merge(const bf16* __restrict__ pA,
                                                  const bf16* __restrict__ pB,
                                                  const float* __restrict__ ml,
                                                  bf16* __restrict__ out) {
  const int j = blockIdx.x;  // 224
  const int t = threadIdx.x;
  int ns, c0, h, qt2;
  if (j < 128) {
    ns = 4; c0 = 4 * j; h = j & 15; qt2 = 8 + (j >> 4);
  } else {
    const int j2 = j - 128;
    ns = 2; c0 = 512 + 2 * j2; h = j2 & 15; qt2 = 2 + (j2 >> 4);
  }
  const int q0 = qt2 * 128;
  const int row0 = t >> 2;
  const int col0 = (t & 3) * 32;

  for (int rg = 0; rg < 2; ++rg) {
    const int row = row0 + rg * 64;
    float m[4], lv[4];
    float M = -1e30f;
    for (int i = 0; i < ns; ++i) {
      m[i] = ml[(c0 + i) * 256 + row];
      lv[i] = ml[(c0 + i) * 256 + 128 + row];
      M = fmaxf(M, m[i]);
    }
    float wsum = 0.f, wgt[4];
    for (int i = 0; i < ns; ++i) {
      wgt[i] = EXP2(m[i] - M);
      wsum += wgt[i] * lv[i];
    }
    const float inv = 1.0f / wsum;

    float accv[32] = {};
    for (int i = 0; i < ns; ++i) {
      const int c = c0 + i;
      const bf16* po =
          (c < 512) ? pA + (size_t)c * 16384 : pB + (size_t)(c - 512) * 16384;
      const bf16* pr = po + row * 128 + col0;
      const float wi = wgt[i];
#pragma unroll
      for (int k = 0; k < 32; ++k) accv[k] += wi * (float)pr[k];
    }
    bf16* o = out + (size_t)(q0 + row) * 2048 + h * 128 + col0;
#pragma unroll
    for (int k = 0; k < 4; ++k) {
      bf16x8 o8;
#pragma unroll
      for (int e = 0; e < 8; ++e) o8[e] = (bf16)(accv[k * 8 + e] * inv);
      *(bf16x8*)(o + k * 8) = o8;
    }
  }
}

extern "C" void kernel_launch(void* const* d_in, const int* in_sizes, int n_in,
                              void* d_out, int out_size, void* d_ws, size_t ws_size,
                              hipStream_t stream) {
  (void)in_sizes; (void)n_in; (void)out_size; (void)ws_size;
  const float* x = (const float*)d_in[0];
  const float* wqkv = (const float*)d_in[1];
  const float* wout = (const float*)d_in[2];
  float* out = (float*)d_out;

  bf16* x_bf = (bf16*)d_ws;                        // [0, 8MB)
  bf16* wqkv_bf = x_bf + (size_t)2048 * 2048;      // [8, 32MB)
  bf16* wout_bf = wqkv_bf + (size_t)6144 * 2048;   // [32, 40MB)
  bf16* qb = wout_bf + (size_t)2048 * 2048;        // [40, 48MB)
  bf16* kb = qb + (size_t)2048 * 2048;             // [48, 56MB)
  bf16* vt = kb + (size_t)2048 * 2048;             // [56, 64MB)
  bf16* attn = wqkv_bf;                            // wqkv dead after GEMM1
  bf16* pA = wqkv_bf + (size_t)2048 * 2048;        // 16MB: chunks 0..511
  bf16* pB = x_bf;                                 // 6MB: chunks 512..703 (x dead)
  float* ml = (float*)((char*)d_ws + (size_t)6 * 1024 * 1024);  // 720KB

  cast_all<<<20480, 256, 0, stream>>>(x, wqkv, wout, x_bf, wqkv_bf, wout_bf);
  gemm1_qkv<<<dim3(48, 16), 256, 0, stream>>>(x_bf, wqkv_bf, qb, kb, vt);
  attn_kernel<<<736, 512, 0, stream>>>(qb, kb, vt, attn, pA, pB, ml);
  attn_merge<<<224, 256, 0, stream>>>(pA, pB, ml, attn);
  gemm2_64x128<<<dim3(16, 32), 256, 0, stream>>>(attn, wout_bf, out);
}

// Round 19
// 167.963 us; speedup vs baseline: 1.0488x; 1.0488x over previous
//
#include <hip/hip_runtime.h>

typedef __bf16 bf16;
typedef __bf16 bf16x8 __attribute__((ext_vector_type(8)));
typedef __bf16 bf16x4 __attribute__((ext_vector_type(4)));
typedef float f32x4 __attribute__((ext_vector_type(4)));

#if __has_builtin(__builtin_amdgcn_exp2f)
#define EXP2(x) __builtin_amdgcn_exp2f(x)
#else
#define EXP2(x) exp2f(x)
#endif

__device__ __forceinline__ void gload_lds16(const void* g, void* l) {
  __builtin_amdgcn_global_load_lds(
      (const __attribute__((address_space(1))) void*)g,
      (__attribute__((address_space(3))) void*)l, 16, 0, 0);
}

// Cast all three inputs, grid-stride at 2048 blocks (G11).
// Layout: [x 4M][wqkv 12M][wout 4M] f32 elems, processed 4/thread.
__global__ __launch_bounds__(256) void cast_all(const float* __restrict__ x,
                                                const float* __restrict__ wqkv,
                                                const float* __restrict__ wout,
                                                bf16* __restrict__ x_bf,
                                                bf16* __restrict__ wqkv_bf,
                                                bf16* __restrict__ wout_bf) {
  const int nchunk = 5 * 1024 * 1024;  // 20M elems / 4
  for (int c = blockIdx.x * 256 + threadIdx.x; c < nchunk; c += 2048 * 256) {
    const float* src;
    bf16* dst;
    int i;
    if (c < 1048576) {
      src = x; dst = x_bf; i = c * 4;
    } else if (c < 4194304) {
      src = wqkv; dst = wqkv_bf; i = (c - 1048576) * 4;
    } else {
      src = wout; dst = wout_bf; i = (c - 4194304) * 4;
    }
    float4 v = *(const float4*)(src + i);
    bf16x4 o = {(bf16)v.x, (bf16)v.y, (bf16)v.z, (bf16)v.w};
    *(bf16x4*)(dst + i) = o;
  }
}

// ---------------------------------------------------------------------------
// GEMM1 (known-good, 69.4us): qkv = x @ w_qkv^T.  m97 128^2, BK=32, constexpr
// dims.  FROZEN: r4/r7/r8/r11/r15/r16 restructures all regressed.
// ---------------------------------------------------------------------------
__global__ __launch_bounds__(256) void gemm1_qkv(const bf16* __restrict__ A,
                                                 const bf16* __restrict__ B,
                                                 bf16* __restrict__ qb,
                                                 bf16* __restrict__ kb,
                                                 bf16* __restrict__ vt) {
  constexpr int K = 2048;
  __shared__ bf16 As[128 * 32];
  __shared__ bf16 Bs[128 * 32];
  const int t = threadIdx.x;
  const int w = t >> 6, l = t & 63;
  const int lr = l & 15, lg = l >> 4;
  const int nwg = 768;
  int lin = blockIdx.y * 48 + blockIdx.x;
  lin = (lin & 7) * (nwg >> 3) + (lin >> 3);  // XCD-bijective
  const int bn = lin % 48;
  const int bm = lin / 48;
  const int wr = w >> 1, wc = w & 1;

  f32x4 acc[4][4] = {};
  const int row0 = t >> 2;
  const int cc0 = (t & 3) * 8;

  for (int k0 = 0; k0 < K; k0 += 32) {
#pragma unroll
    for (int r = 0; r < 2; ++r) {
      const int row = r * 64 + row0;
      gload_lds16(A + (size_t)(bm * 128 + row) * K + k0 + cc0,
                  (char*)As + (r * 256 + w * 64) * 16);
      gload_lds16(B + (size_t)(bn * 128 + row) * K + k0 + cc0,
                  (char*)Bs + (r * 256 + w * 64) * 16);
    }
    __syncthreads();
    bf16x8 af[4], bfr[4];
#pragma unroll
    for (int i = 0; i < 4; ++i) {
      af[i] = *(const bf16x8*)((const char*)As + (wr * 64 + i * 16 + lr) * 64 + lg * 16);
      bfr[i] = *(const bf16x8*)((const char*)Bs + (wc * 64 + i * 16 + lr) * 64 + lg * 16);
    }
#pragma unroll
    for (int mi = 0; mi < 4; ++mi)
#pragma unroll
      for (int ni = 0; ni < 4; ++ni)
        acc[mi][ni] = __builtin_amdgcn_mfma_f32_16x16x32_bf16(af[mi], bfr[ni],
                                                              acc[mi][ni], 0, 0, 0);
    __syncthreads();
  }

  const int mb = bm * 128 + wr * 64 + lg * 4;
  const int nb = bn * 128 + wc * 64 + lr;
  if (bn * 128 < 4096) {
    bf16* dst = (bn * 128 < 2048) ? qb : kb;
#pragma unroll
    for (int mi = 0; mi < 4; ++mi) {
      const int mg = mb + mi * 16;
#pragma unroll
      for (int ni = 0; ni < 4; ++ni) {
        const int ng = (nb + ni * 16) & 2047;
#pragma unroll
        for (int rr = 0; rr < 4; ++rr)
          dst[(size_t)(mg + rr) * 2048 + ng] = (bf16)acc[mi][ni][rr];
      }
    }
  } else {
#pragma unroll
    for (int mi = 0; mi < 4; ++mi) {
      const int mg = mb + mi * 16;
#pragma unroll
      for (int ni = 0; ni < 4; ++ni) {
        const int dc = nb + ni * 16 - 4096;
        bf16x4 pk = {(bf16)acc[mi][ni][0], (bf16)acc[mi][ni][1],
                     (bf16)acc[mi][ni][2], (bf16)acc[mi][ni][3]};
        *(bf16x4*)(vt + (size_t)dc * 2048 + mg) = pk;
      }
    }
  }
}

// ---------------------------------------------------------------------------
// GEMM2 (known-good): out = attn @ w_out^T, f32.  64x128 tile, 512 blocks.
// ---------------------------------------------------------------------------
__global__ __launch_bounds__(256) void gemm2_64x128(const bf16* __restrict__ A,
                                                    const bf16* __restrict__ B,
                                                    float* __restrict__ Cf) {
  constexpr int K = 2048, N = 2048;
  __shared__ bf16 As[64 * 32];
  __shared__ bf16 Bs[128 * 32];
  const int t = threadIdx.x;
  const int w = t >> 6, l = t & 63;
  const int lr = l & 15, lg = l >> 4;
  int lin = blockIdx.y * 16 + blockIdx.x;
  lin = (lin & 7) * 64 + (lin >> 3);  // XCD-bijective
  const int bn = lin % 16;
  const int bm = lin / 16;

  f32x4 acc[4][2] = {};

  for (int k0 = 0; k0 < K; k0 += 32) {
    {
      const int row = t >> 2;
      gload_lds16(A + (size_t)(bm * 64 + row) * K + k0 + (t & 3) * 8,
                  (char*)As + (w * 64) * 16);
    }
#pragma unroll
    for (int r = 0; r < 2; ++r) {
      const int c = r * 256 + t;
      const int row = c >> 2;
      gload_lds16(B + (size_t)(bn * 128 + row) * K + k0 + (c & 3) * 8,
                  (char*)Bs + (r * 256 + w * 64) * 16);
    }
    __syncthreads();
    bf16x8 af[4], bfr[2];
#pragma unroll
    for (int i = 0; i < 4; ++i)
      af[i] = *(const bf16x8*)((const char*)As + (i * 16 + lr) * 64 + lg * 16);
#pragma unroll
    for (int i = 0; i < 2; ++i)
      bfr[i] = *(const bf16x8*)((const char*)Bs + (w * 32 + i * 16 + lr) * 64 + lg * 16);
#pragma unroll
    for (int mi = 0; mi < 4; ++mi)
#pragma unroll
      for (int ni = 0; ni < 2; ++ni)
        acc[mi][ni] = __builtin_amdgcn_mfma_f32_16x16x32_bf16(af[mi], bfr[ni],
                                                              acc[mi][ni], 0, 0, 0);
    __syncthreads();
  }

  const int mb = bm * 64 + lg * 4;
  const int nb = bn * 128 + w * 32 + lr;
#pragma unroll
  for (int mi = 0; mi < 4; ++mi) {
    const int mg = mb + mi * 16;
#pragma unroll
    for (int ni = 0; ni < 2; ++ni) {
      const int ng = nb + ni * 16;
#pragma unroll
      for (int rr = 0; rr < 4; ++rr)
        Cf[(size_t)(mg + rr) * N + ng] = acc[mi][ni][rr];
    }
  }
}

// ---------------------------------------------------------------------------
// Flash attention (known-good r14/r17): QBLK=64, causal + ALiBi + window W=24;
// tiered KV split; single-buffered LDS staging (40KB, 4 blocks/CU).
// Grid 1408:
//   b in [0,1024):    4-way piece b&3 of job j=b>>2    (h=j&15, qt=16+(j>>4))
//   b in [1024,1280): 2-way piece of job j=(b-1024)>>1 (h=j&15, qt=8+(j>>4))
//   b in [1280,1408): single i=b-1280                  (h=i&15, qt=i>>4 < 8)
// ---------------------------------------------------------------------------
__global__ __launch_bounds__(256) void attn_kernel(const bf16* __restrict__ qb,
                                                   const bf16* __restrict__ kb,
                                                   const bf16* __restrict__ vt,
                                                   bf16* __restrict__ out,
                                                   bf16* __restrict__ pA,
                                                   bf16* __restrict__ pB,
                                                   float* __restrict__ ml) {
  constexpr int S = 2048, D = 2048;
  __shared__ bf16 Ks[64 * 128];
  __shared__ bf16 Vs[128 * 64];
  __shared__ bf16 Ps[4][16 * 64];
  const int t = threadIdx.x;
  const int w = t >> 6, l = t & 63;
  const int lr = l & 15, lg = l >> 4;
  const int b = blockIdx.x;

  int h, qt, piece, ns;
  if (b < 1024) {
    const int j = b >> 2;
    h = j & 15; qt = 16 + (j >> 4); piece = b & 3; ns = 4;
  } else if (b < 1280) {
    const int j = (b - 1024) >> 1;
    h = j & 15; qt = 8 + (j >> 4); piece = (b - 1024) & 1; ns = 2;
  } else {
    const int i = b - 1280;
    h = i & 15; qt = i >> 4; piece = 0; ns = 1;
  }
  const bool split = (ns > 1);
  const int q0 = qt * 64;
  const float slope2 = exp2f(-0.5f * (float)(h + 1)) * 1.4426950408889634f;
  const float scale2 = 0.08838834764831845f * 1.4426950408889634f;
  const int W = (int)(24.0f / slope2);
  const int s0 = (q0 > W) ? ((q0 - W) >> 6) : 0;
  const int len = qt + 1 - s0;
  const int start = s0 + (len * piece) / ns;
  const int end = s0 + (len * (piece + 1)) / ns;

  bf16x8 qf[4];
  {
    const bf16* qrow = qb + (size_t)(q0 + w * 16 + lr) * D + h * 128 + lg * 8;
#pragma unroll
    for (int kk = 0; kk < 4; ++kk) qf[kk] = *(const bf16x8*)(qrow + kk * 32);
  }

  f32x4 ob[8] = {};
  float mrow[4] = {-1e30f, -1e30f, -1e30f, -1e30f};
  float lrow[4] = {0.f, 0.f, 0.f, 0.f};

  auto stage = [&](int kv0) {
#pragma unroll
    for (int r = 0; r < 4; ++r) {
      {
        const int krow = r * 16 + (t >> 4);
        const int kcc = t & 15;
        gload_lds16(kb + (size_t)(kv0 + krow) * D + h * 128 + ((kcc ^ (krow & 7)) * 8),
                    (char*)Ks + (r * 256 + w * 64) * 16);
      }
      {
        const int vrow = r * 32 + (t >> 3);
        const int vcc = t & 7;
        gload_lds16(vt + (size_t)(h * 128 + vrow) * S + kv0 + ((vcc ^ (vrow & 7)) * 8),
                    (char*)Vs + (r * 256 + w * 64) * 16);
      }
    }
  };

  for (int tile = start; tile < end; ++tile) {
    const int kv0 = tile << 6;
    stage(kv0);
    __syncthreads();

    f32x4 sc[4] = {};
    __builtin_amdgcn_s_setprio(1);
#pragma unroll
    for (int jb = 0; jb < 4; ++jb) {
      const int row = jb * 16 + lr;
#pragma unroll
      for (int kk = 0; kk < 4; ++kk) {
        const int byte = row * 256 + ((kk * 64 + lg * 16) ^ ((row & 7) << 4));
        bf16x8 kf = *(const bf16x8*)((const char*)Ks + byte);
        sc[jb] = __builtin_amdgcn_mfma_f32_16x16x32_bf16(qf[kk], kf, sc[jb], 0, 0, 0);
      }
    }
    __builtin_amdgcn_s_setprio(0);

    float bias[4];
#pragma unroll
    for (int jb = 0; jb < 4; ++jb)
      bias[jb] = slope2 * (float)(kv0 + jb * 16 + lr - (S - 1));
    const bool diag = (tile == qt);
    float xv[4][4], m2r[4];
#pragma unroll
    for (int rr = 0; rr < 4; ++rr) {
#pragma unroll
      for (int jb = 0; jb < 4; ++jb) {
        float v = fmaf(sc[jb][rr], scale2, bias[jb]);
        if (diag && (jb * 16 + lr > w * 16 + lg * 4 + rr)) v = -1e30f;
        xv[rr][jb] = v;
      }
      float m2 = fmaxf(fmaxf(xv[rr][0], xv[rr][1]), fmaxf(xv[rr][2], xv[rr][3]));
      m2 = fmaxf(m2, __shfl_xor(m2, 1));
      m2 = fmaxf(m2, __shfl_xor(m2, 2));
      m2 = fmaxf(m2, __shfl_xor(m2, 4));
      m2 = fmaxf(m2, __shfl_xor(m2, 8));
      m2r[rr] = m2;
    }
    float need = fmaxf(fmaxf(m2r[0] - mrow[0], m2r[1] - mrow[1]),
                       fmaxf(m2r[2] - mrow[2], m2r[3] - mrow[3]));
    if (!__all(need <= 8.0f)) {
#pragma unroll
      for (int rr = 0; rr < 4; ++rr) {
        const float mnew = fmaxf(mrow[rr], m2r[rr]);
        const float cf = EXP2(mrow[rr] - mnew);
        lrow[rr] *= cf;
        mrow[rr] = mnew;
#pragma unroll
        for (int db = 0; db < 8; ++db) ob[db][rr] *= cf;
      }
    }
    char* pbase = (char*)Ps[w];
#pragma unroll
    for (int rr = 0; rr < 4; ++rr) {
      const int prow = lg * 4 + rr;
      const int sw = (prow & 7) << 4;
      float ps = 0.f;
#pragma unroll
      for (int jb = 0; jb < 4; ++jb) {
        const float p = EXP2(xv[rr][jb] - mrow[rr]);
        *(bf16*)(pbase + ((prow * 128 + jb * 32 + lr * 2) ^ sw)) = (bf16)p;
        ps += p;
      }
      lrow[rr] += ps;
    }

    bf16x8 pf[2];
#pragma unroll
    for (int s = 0; s < 2; ++s)
      pf[s] = *(const bf16x8*)(pbase + ((lr * 128 + s * 64 + lg * 16) ^ ((lr & 7) << 4)));
    __builtin_amdgcn_s_setprio(1);
#pragma unroll
    for (int db = 0; db < 8; ++db) {
      const int vrow = db * 16 + lr;
#pragma unroll
      for (int s = 0; s < 2; ++s) {
        const int byte = vrow * 128 + ((s * 64 + lg * 16) ^ ((vrow & 7) << 4));
        bf16x8 vf = *(const bf16x8*)((const char*)Vs + byte);
        ob[db] = __builtin_amdgcn_mfma_f32_16x16x32_bf16(pf[s], vf, ob[db], 0, 0, 0);
      }
    }
    __builtin_amdgcn_s_setprio(0);
    __syncthreads();
  }

  if (!split) {
#pragma unroll
    for (int rr = 0; rr < 4; ++rr) {
      float ls = lrow[rr];
      ls += __shfl_xor(ls, 1);
      ls += __shfl_xor(ls, 2);
      ls += __shfl_xor(ls, 4);
      ls += __shfl_xor(ls, 8);
      const float inv = 1.0f / ls;
      const int mg = q0 + w * 16 + lg * 4 + rr;
#pragma unroll
      for (int db = 0; db < 8; ++db)
        out[(size_t)mg * D + h * 128 + db * 16 + lr] = (bf16)(ob[db][rr] * inv);
    }
  } else {
    bf16* po = (b < 1024) ? pA + (size_t)b * 8192 : pB + (size_t)(b - 1024) * 8192;
#pragma unroll
    for (int rr = 0; rr < 4; ++rr) {
      float ls = lrow[rr];
      ls += __shfl_xor(ls, 1);
      ls += __shfl_xor(ls, 2);
      ls += __shfl_xor(ls, 4);
      ls += __shfl_xor(ls, 8);
      const int row = w * 16 + lg * 4 + rr;
#pragma unroll
      for (int db = 0; db < 8; ++db)
        po[row * 128 + db * 16 + lr] = (bf16)ob[db][rr];
      if (lr == 0) {
        ml[b * 128 + row] = mrow[rr];
        ml[b * 128 + 64 + row] = ls;
      }
    }
  }
}

// Merge ns KV pieces of a split job (exact log-sum-exp combine).
__global__ __launch_bounds__(256) void attn_merge(const bf16* __restrict__ pA,
                                                  const bf16* __restrict__ pB,
                                                  const float* __restrict__ ml,
                                                  bf16* __restrict__ out) {
  const int j = blockIdx.x;  // 384
  const int t = threadIdx.x;
  int ns, c0, h, qt;
  if (j < 256) {
    ns = 4; c0 = 4 * j; h = j & 15; qt = 16 + (j >> 4);
  } else {
    const int j2 = j - 256;
    ns = 2; c0 = 1024 + 2 * j2; h = j2 & 15; qt = 8 + (j2 >> 4);
  }
  const int q0 = qt * 64;
  const int row = t >> 2;
  const int col0 = (t & 3) * 32;

  float m[4], lv[4];
  float M = -1e30f;
  for (int i = 0; i < ns; ++i) {
    m[i] = ml[(c0 + i) * 128 + row];
    lv[i] = ml[(c0 + i) * 128 + 64 + row];
    M = fmaxf(M, m[i]);
  }
  float wsum = 0.f, wgt[4];
  for (int i = 0; i < ns; ++i) {
    wgt[i] = EXP2(m[i] - M);
    wsum += wgt[i] * lv[i];
  }
  const float inv = 1.0f / wsum;

  float accv[32] = {};
  for (int i = 0; i < ns; ++i) {
    const int c = c0 + i;
    const bf16* po = (c < 1024) ? pA + (size_t)c * 8192 : pB + (size_t)(c - 1024) * 8192;
    const bf16* pr = po + row * 128 + col0;
    const float wi = wgt[i];
#pragma unroll
    for (int k = 0; k < 32; ++k) accv[k] += wi * (float)pr[k];
  }
  bf16* o = out + (size_t)(q0 + row) * 2048 + h * 128 + col0;
#pragma unroll
  for (int k = 0; k < 4; ++k) {
    bf16x8 o8;
#pragma unroll
    for (int e = 0; e < 8; ++e) o8[e] = (bf16)(accv[k * 8 + e] * inv);
    *(bf16x8*)(o + k * 8) = o8;
  }
}

extern "C" void kernel_launch(void* const* d_in, const int* in_sizes, int n_in,
                              void* d_out, int out_size, void* d_ws, size_t ws_size,
                              hipStream_t stream) {
  (void)in_sizes; (void)n_in; (void)out_size; (void)ws_size;
  const float* x = (const float*)d_in[0];
  const float* wqkv = (const float*)d_in[1];
  const float* wout = (const float*)d_in[2];
  float* out = (float*)d_out;

  bf16* x_bf = (bf16*)d_ws;                        // [0, 8MB)
  bf16* wqkv_bf = x_bf + (size_t)2048 * 2048;      // [8, 32MB)
  bf16* wout_bf = wqkv_bf + (size_t)6144 * 2048;   // [32, 40MB)
  bf16* qb = wout_bf + (size_t)2048 * 2048;        // [40, 48MB)
  bf16* kb = qb + (size_t)2048 * 2048;             // [48, 56MB)
  bf16* vt = kb + (size_t)2048 * 2048;             // [56, 64MB)
  bf16* attn = wqkv_bf;                            // wqkv dead after GEMM1
  bf16* pA = wqkv_bf + (size_t)2048 * 2048;        // 16MB: chunks 0..1023
  bf16* pB = x_bf;                                 // 4MB: chunks 1024..1279 (x dead)
  float* ml = (float*)((char*)d_ws + (size_t)4 * 1024 * 1024);  // 655KB

  cast_all<<<2048, 256, 0, stream>>>(x, wqkv, wout, x_bf, wqkv_bf, wout_bf);
  gemm1_qkv<<<dim3(48, 16), 256, 0, stream>>>(x_bf, wqkv_bf, qb, kb, vt);
  attn_kernel<<<1408, 256, 0, stream>>>(qb, kb, vt, attn, pA, pB, ml);
  attn_merge<<<384, 256, 0, stream>>>(pA, pB, ml, attn);
  gemm2_64x128<<<dim3(16, 32), 256, 0, stream>>>(attn, wout_bf, out);
}